// Round 6
// baseline (929.692 us; speedup 1.0000x reference)
//
#include <hip/hip_runtime.h>
#include <math.h>
#include <type_traits>

#define DIMK 2048
#define NEMB 16384
#define NB 256
#define NR2 1536          // 256*6 neighbor rows
#define NBLK 128          // n-blocks
#define INV_BETA 20.0f
#define NEG_INF (-3.0e38f)

typedef short short8 __attribute__((ext_vector_type(8)));
typedef float f32x4 __attribute__((ext_vector_type(4)));

__device__ __forceinline__ unsigned short f2bf(float f) {
  unsigned u = __float_as_uint(f);
  u += 0x7fffu + ((u >> 16) & 1u);
  return (unsigned short)(u >> 16);
}

__device__ __forceinline__ void ins6(float x, float v[6]) {
  if (x > v[5]) {
    v[5] = x;
#pragma unroll
    for (int j = 5; j > 0; j--) {
      if (v[j] > v[j - 1]) { float tmp = v[j]; v[j] = v[j - 1]; v[j - 1] = tmp; }
    }
  }
}

// top-6 insert with (value desc, index asc) tie-break — matches jax top_k order
__device__ __forceinline__ void ins6i(float x, int xi, float v[6], int vi[6]) {
  if (x > v[5] || (x == v[5] && xi < vi[5])) {
    v[5] = x; vi[5] = xi;
#pragma unroll
    for (int j = 5; j > 0; j--) {
      if (v[j] > v[j - 1] || (v[j] == v[j - 1] && vi[j] < vi[j - 1])) {
        float tv = v[j]; v[j] = v[j - 1]; v[j - 1] = tv;
        int ti = vi[j]; vi[j] = vi[j - 1]; vi[j - 1] = ti;
      }
    }
  }
}

__global__ __launch_bounds__(256) void cvt_kernel(const float* __restrict__ src,
                                                  unsigned short* __restrict__ dst, int n4) {
  int i = blockIdx.x * 256 + threadIdx.x;
  if (i < n4) {
    float4 f = ((const float4*)src)[i];
    ushort4 o;
    o.x = f2bf(f.x); o.y = f2bf(f.y); o.z = f2bf(f.z); o.w = f2bf(f.w);
    ((ushort4*)dst)[i] = o;
  }
}

// Register-direct GEMM (flatmm style): each lane global_load_dwordx4's its own
// MFMA fragment (row = l16, kseg = quad — same mapping the LDS path used), one
// 32-k step ahead (manual 2x unrolled pipeline). No global_load_lds, no K-loop
// barriers: the old structure paid a full vmcnt(0) drain (600-900 cyc A-gather
// latency) at __syncthreads EVERY iter (1770 cyc/block-iter vs m97's 736), and
// its DMA port contention was the invariant 7.6e7 SQ_LDS_BANK_CONFLICT.
// 2x fetch duplication (waves don't share) = 42 B/cyc/CU from L2/L3, under the
// 56 B/cyc L2 ceiling; HBM traffic unchanged (em is L3-resident).
struct EpM0 {                       // logits gemm fused-stats epilogue (~31 KB)
  float ct[32 * 133];
  float p6v[32 * 8 * 6];
  int   p6i[32 * 8 * 6];
  float ms[32 * 8 * 2];
};
struct EpM1 {                       // sims gemm top-6 epilogue (~23.3 KB)
  float ct[32 * 133];
  float p6[32 * 49];
};

// MODE 0: C = X(256xK) * em^T * 20 -> per-(row,128col-block) top6(v,i) + (max,sumexp)
//         tile 64x128, grid (128,4); all waves wr=0, wc=wave (32-col groups)
// MODE 1: C = em[nidx](1536xK) * em^T -> per-(row,128col-block) top-6 partials
//         tile 128x128, grid (128,12); wr=wave>>1, wc=wave&1
template <int MODE>
__global__ __launch_bounds__(256, 3) void gemm_kernel(
    const unsigned short* __restrict__ Abase, const unsigned short* __restrict__ Bbase,
    const int* __restrict__ nidx, float* __restrict__ p1, float* __restrict__ p2,
    float* __restrict__ p3, float* __restrict__ p4) {
  constexpr int MI = 4;
  constexpr int NI = (MODE == 0) ? 2 : 4;

  using Ep = typename std::conditional<MODE == 0, EpM0, EpM1>::type;
  __shared__ Ep ep;
  __shared__ int rowIdxSh[128];
  int t = threadIdx.x;
  int lane = t & 63, wave = t >> 6;
  int quad = lane >> 4, l16 = lane & 15;
  int wr = (MODE == 0) ? 0 : (wave >> 1);
  int wc = (MODE == 0) ? wave : (wave & 1);
  int bn = blockIdx.x, bm = blockIdx.y;

  if constexpr (MODE == 1) {
    if (t < 128) rowIdxSh[t] = nidx[bm * 128 + t];
    __syncthreads();
  }

  // per-lane fragment base pointers (16B-aligned; row*4KB + quad*16B)
  const unsigned short* ap[MI];
  const unsigned short* bp[NI];
#pragma unroll
  for (int mi = 0; mi < MI; mi++) {
    int r = wr * 64 + mi * 16 + l16;
    int grow = (MODE == 0) ? (bm * 64 + mi * 16 + l16) : rowIdxSh[r];
    ap[mi] = Abase + (size_t)grow * DIMK + quad * 8;
  }
#pragma unroll
  for (int ni = 0; ni < NI; ni++) {
    int r = bn * 128 + ((MODE == 0) ? wave * 32 : wc * 64) + ni * 16 + l16;
    bp[ni] = Bbase + (size_t)r * DIMK + quad * 8;
  }

  f32x4 acc[MI][NI];
#pragma unroll
  for (int mi = 0; mi < MI; mi++)
#pragma unroll
    for (int ni = 0; ni < NI; ni++) acc[mi][ni] = (f32x4)0.0f;

  short8 a0[MI], b0[NI], a1[MI], b1[NI];
#pragma unroll
  for (int mi = 0; mi < MI; mi++) a0[mi] = *(const short8*)(ap[mi]);
#pragma unroll
  for (int ni = 0; ni < NI; ni++) b0[ni] = *(const short8*)(bp[ni]);

#pragma unroll 1
  for (int k0 = 0; k0 < DIMK; k0 += 64) {
#pragma unroll
    for (int mi = 0; mi < MI; mi++) a1[mi] = *(const short8*)(ap[mi] + k0 + 32);
#pragma unroll
    for (int ni = 0; ni < NI; ni++) b1[ni] = *(const short8*)(bp[ni] + k0 + 32);
#pragma unroll
    for (int mi = 0; mi < MI; mi++)
#pragma unroll
      for (int ni = 0; ni < NI; ni++)
        acc[mi][ni] = __builtin_amdgcn_mfma_f32_16x16x32_bf16(a0[mi], b0[ni], acc[mi][ni], 0, 0, 0);
    if (k0 + 64 < DIMK) {
#pragma unroll
      for (int mi = 0; mi < MI; mi++) a0[mi] = *(const short8*)(ap[mi] + k0 + 64);
#pragma unroll
      for (int ni = 0; ni < NI; ni++) b0[ni] = *(const short8*)(bp[ni] + k0 + 64);
    }
#pragma unroll
    for (int mi = 0; mi < MI; mi++)
#pragma unroll
      for (int ni = 0; ni < NI; ni++)
        acc[mi][ni] = __builtin_amdgcn_mfma_f32_16x16x32_bf16(a1[mi], b1[ni], acc[mi][ni], 0, 0, 0);
  }

  if constexpr (MODE == 0) {
    // fused logits stats: per (row, bn) -> top6 (value, global col) + (max, sumexp)
    float* pt6v = p1; float* pt6i_f = p2; float* pmx = p3; float* pse = p4;
    int* pt6i = (int*)pt6i_f;
#pragma unroll
    for (int ph = 0; ph < 2; ph++) {     // 32 rows per phase
#pragma unroll
      for (int mi2 = 0; mi2 < 2; mi2++) {
        int mi = ph * 2 + mi2;
#pragma unroll
        for (int ni = 0; ni < 2; ni++)
#pragma unroll
          for (int rr = 0; rr < 4; rr++)
            ep.ct[(mi2 * 16 + quad * 4 + rr) * 133 + wave * 32 + ni * 16 + l16] =
                acc[mi][ni][rr] * INV_BETA;
      }
      __syncthreads();
      {
        int srow = t & 31, sseg = t >> 5;   // 8 segs x 16 cols
        float vv[16];
        const float* basep = &ep.ct[srow * 133 + sseg * 16];
#pragma unroll
        for (int i = 0; i < 16; i++) vv[i] = basep[i];
        float v[6]; int vi[6];
#pragma unroll
        for (int j = 0; j < 6; j++) { v[j] = NEG_INF; vi[j] = 0x7fffffff; }
        int gcol0 = bn * 128 + sseg * 16;
#pragma unroll
        for (int i = 0; i < 16; i++) ins6i(vv[i], gcol0 + i, v, vi);
        float mloc = v[0];
        float se = 0.f;
#pragma unroll
        for (int i = 0; i < 16; i++) se += expf(vv[i] - mloc);
        int slot = srow * 8 + sseg;
#pragma unroll
        for (int j = 0; j < 6; j++) { ep.p6v[slot * 6 + j] = v[j]; ep.p6i[slot * 6 + j] = vi[j]; }
        ep.ms[slot * 2] = mloc; ep.ms[slot * 2 + 1] = se;
      }
      __syncthreads();
      if (t < 32) {
        float v[6]; int vi[6];
#pragma unroll
        for (int j = 0; j < 6; j++) { v[j] = NEG_INF; vi[j] = 0x7fffffff; }
        float M = NEG_INF, S = 0.f;
#pragma unroll
        for (int s = 0; s < 8; s++) {
          int slot = t * 8 + s;
#pragma unroll
          for (int j = 0; j < 6; j++) ins6i(ep.p6v[slot * 6 + j], ep.p6i[slot * 6 + j], v, vi);
          float mo = ep.ms[slot * 2], so = ep.ms[slot * 2 + 1];
          float Mn = fmaxf(M, mo);
          S = S * expf(M - Mn) + so * expf(mo - Mn);
          M = Mn;
        }
        int rowg = bm * 64 + ph * 32 + t;
        size_t base = ((size_t)rowg * NBLK + bn);
#pragma unroll
        for (int j = 0; j < 6; j++) { pt6v[base * 6 + j] = v[j]; pt6i[base * 6 + j] = vi[j]; }
        pmx[base] = M; pse[base] = S;
      }
      __syncthreads();
    }
  } else {
    float* part6 = p1;
#pragma unroll
    for (int ph = 0; ph < 4; ph++) {       // 32 tile-rows per phase
      int phwr = ph >> 1, phmi0 = (ph & 1) * 2;
      if (wr == phwr) {
#pragma unroll
        for (int mi2 = 0; mi2 < 2; mi2++) {
          int mi = phmi0 + mi2;
#pragma unroll
          for (int ni = 0; ni < 4; ni++)
#pragma unroll
            for (int rr = 0; rr < 4; rr++)
              ep.ct[(mi2 * 16 + quad * 4 + rr) * 133 + wc * 64 + ni * 16 + l16] =
                  acc[mi][ni][rr];
        }
      }
      __syncthreads();
      {
        int srow = t & 31, sseg = t >> 5;   // 8 segs x 16 cols
        float v[6] = {NEG_INF, NEG_INF, NEG_INF, NEG_INF, NEG_INF, NEG_INF};
        const float* basep = &ep.ct[srow * 133 + sseg * 16];
#pragma unroll
        for (int i = 0; i < 16; i++) ins6(basep[i], v);
#pragma unroll
        for (int j = 0; j < 6; j++) ep.p6[srow * 49 + sseg * 6 + j] = v[j];
      }
      __syncthreads();
      if (t < 32) {
        float v[6] = {NEG_INF, NEG_INF, NEG_INF, NEG_INF, NEG_INF, NEG_INF};
        const float* pp = &ep.p6[t * 49];
        for (int i = 0; i < 48; i++) ins6(pp[i], v);
        int rg = bm * 128 + ph * 32 + t;
        float* dst = part6 + ((size_t)rg * NBLK + bn) * 6;
#pragma unroll
        for (int j = 0; j < 6; j++) dst[j] = v[j];
      }
      __syncthreads();
    }
  }
}

// one wave per logit row: merge 128 per-block partials -> global top6 + lse
__global__ __launch_bounds__(256) void mergestats_kernel(
    const float* __restrict__ pt6v, const int* __restrict__ pt6i,
    const float* __restrict__ pmx, const float* __restrict__ pse,
    float* __restrict__ topv, int* __restrict__ topi, float* __restrict__ lse) {
  int gid = blockIdx.x * 256 + threadIdx.x;
  int m = gid >> 6, lane = gid & 63;
  if (m >= NB) return;
  float v[6]; int vi[6];
#pragma unroll
  for (int j = 0; j < 6; j++) { v[j] = NEG_INF; vi[j] = 0x7fffffff; }
  size_t rb = (size_t)m * NBLK;
#pragma unroll
  for (int a = 0; a < 12; a++) {        // 768 entries / 64 lanes
    int e = lane + a * 64;
    ins6i(pt6v[rb * 6 + e], pt6i[rb * 6 + e], v, vi);
  }
  float M = pmx[rb + lane], S = pse[rb + lane];
  {
    float mo = pmx[rb + lane + 64], so = pse[rb + lane + 64];
    float Mn = fmaxf(M, mo);
    S = S * expf(M - Mn) + so * expf(mo - Mn);
    M = Mn;
  }
#pragma unroll
  for (int off = 32; off > 0; off >>= 1) {
    float ov[6]; int oi[6];
#pragma unroll
    for (int j = 0; j < 6; j++) { ov[j] = __shfl_xor(v[j], off, 64); oi[j] = __shfl_xor(vi[j], off, 64); }
#pragma unroll
    for (int j = 0; j < 6; j++) ins6i(ov[j], oi[j], v, vi);
    float oM = __shfl_xor(M, off, 64), oS = __shfl_xor(S, off, 64);
    float Mn = fmaxf(M, oM);
    S = S * expf(M - Mn) + oS * expf(oM - Mn);
    M = Mn;
  }
  if (lane == 0) {
    lse[m] = M + logf(S);
#pragma unroll
    for (int j = 0; j < 6; j++) { topv[m * 6 + j] = v[j]; topi[m * 6 + j] = vi[j]; }
  }
}

// w < NR2: sa[w] = em[topi[w]] . em[anchor];  w in [NR2, NR2+NB): tl[m] = 20 * x[m].em[tgt[m]]
__global__ __launch_bounds__(256) void sa_kernel(const float* __restrict__ em,
                                                 const float* __restrict__ x,
                                                 const int* __restrict__ topi,
                                                 const int* __restrict__ targets,
                                                 float* __restrict__ sa,
                                                 float* __restrict__ tl) {
  int gid = blockIdx.x * 256 + threadIdx.x;
  int w = gid >> 6, lane = gid & 63;
  if (w >= NR2 + NB) return;
  const float* ei; const float* ea;
  if (w < NR2) {
    int m = w / 6;
    ei = em + (size_t)topi[w] * DIMK;
    ea = em + (size_t)topi[m * 6] * DIMK;
  } else {
    int m = w - NR2;
    ei = x + (size_t)m * DIMK;
    ea = em + (size_t)targets[m] * DIMK;
  }
  float s = 0.f;
  for (int d = lane; d < DIMK; d += 64) s += ei[d] * ea[d];
#pragma unroll
  for (int off = 32; off > 0; off >>= 1) s += __shfl_down(s, off, 64);
  if (lane == 0) {
    if (w < NR2) sa[w] = s;
    else tl[w - NR2] = s * INV_BETA;
  }
}

// recip[r] = 1 iff anchor-sim >= 6th-largest of sims row r
// == (count of partial-top6 values strictly greater than sa) < 6
__global__ __launch_bounds__(256) void stage2_kernel(const float* __restrict__ part6,
                                                     const float* __restrict__ sa,
                                                     int* __restrict__ recip) {
  int gid = blockIdx.x * 256 + threadIdx.x;
  int w = gid >> 6, lane = gid & 63;
  if (w >= NR2) return;
  float s = sa[w];
  const float* p = part6 + (size_t)w * (NBLK * 6);
  int cnt = 0;
  for (int i = lane; i < NBLK * 6; i += 64) cnt += (p[i] > s) ? 1 : 0;
#pragma unroll
  for (int off = 32; off > 0; off >>= 1) cnt += __shfl_down(cnt, off, 64);
  if (lane == 0) recip[w] = (cnt < 6) ? 1 : 0;
}

__global__ __launch_bounds__(256) void final_kernel(
    const float* __restrict__ tl_arr, const float* __restrict__ topv,
    const int* __restrict__ topi, const float* __restrict__ lse_arr,
    const int* __restrict__ recip, const int* __restrict__ targets,
    float* __restrict__ out) {
  int m = threadIdx.x;
  float lse = lse_arr[m];
  int tgt = targets[m];
  float tl = tl_arr[m];
  float beta = 0.f, Ps = 0.f, nbp = 0.f;
  bool tin = false;
#pragma unroll
  for (int k = 0; k < 6; k++) {
    int idx = topi[m * 6 + k]; float v = topv[m * 6 + k];
    float p = expf(v - lse);
    if (idx == tgt) { tin = true; beta += (lse - v); Ps += p; }
    else if (recip[m * 6 + k]) { beta += 0.5f * (lse - v); Ps += p; nbp += p; }
  }
  if (!tin) { beta += (lse - tl); Ps += expf(tl - lse); }
  float alpha = 9.2103404f * (1.f - Ps) + 0.6931472f * nbp;
  __shared__ float sA[256], sB2[256];
  sA[m] = alpha; sB2[m] = beta;
  __syncthreads();
  for (int s = 128; s > 0; s >>= 1) {
    if (m < s) { sA[m] += sA[m + s]; sB2[m] += sB2[m + s]; }
    __syncthreads();
  }
  if (m == 0) { out[0] = 0.05f * sA[0] / 256.f; out[1] = sB2[0] / 256.f; }
}

extern "C" void kernel_launch(void* const* d_in, const int* in_sizes, int n_in,
                              void* d_out, int out_size, void* d_ws, size_t ws_size,
                              hipStream_t stream) {
  const float* x = (const float*)d_in[0];
  const float* em = (const float*)d_in[1];
  const int* targets = (const int*)d_in[2];
  char* ws = (char*)d_ws;
  unsigned short* em_bf = (unsigned short*)ws;                 // 67108864 B
  unsigned short* x_bf  = (unsigned short*)(ws + 67108864);    // 1048576 B
  float* pt6v   = (float*)(ws + 68157440);                     // 786432 B
  float* pt6i_f = (float*)(ws + 68943872);                     // 786432 B
  float* pmx    = (float*)(ws + 69730304);                     // 131072 B
  float* pse    = (float*)(ws + 69861376);                     // 131072 B
  float* part6  = (float*)(ws + 69992448);                     // 4718592 B
  float* topv   = (float*)(ws + 74711040);                     // 6144 B
  int*   topi   = (int*)  (ws + 74717184);                     // 6144 B
  float* lse    = (float*)(ws + 74723328);                     // 1024 B
  float* sa     = (float*)(ws + 74724352);                     // 6144 B
  int*   recip  = (int*)  (ws + 74730496);                     // 6144 B
  float* tl     = (float*)(ws + 74736640);                     // 1024 B

  cvt_kernel<<<dim3(32768), dim3(256), 0, stream>>>(em, em_bf, NEMB * DIMK / 4);
  cvt_kernel<<<dim3(512), dim3(256), 0, stream>>>(x, x_bf, NB * DIMK / 4);
  gemm_kernel<0><<<dim3(128, 4), dim3(256), 0, stream>>>(x_bf, em_bf, (const int*)nullptr,
                                                         pt6v, pt6i_f, pmx, pse);
  mergestats_kernel<<<dim3(64), dim3(256), 0, stream>>>(pt6v, (const int*)pt6i_f, pmx, pse,
                                                        topv, topi, lse);
  sa_kernel<<<dim3(448), dim3(256), 0, stream>>>(em, x, topi, targets, sa, tl);
  gemm_kernel<1><<<dim3(128, 12), dim3(256), 0, stream>>>(em_bf, em_bf, topi,
                                                          part6, (float*)nullptr,
                                                          (float*)nullptr, (float*)nullptr);
  stage2_kernel<<<dim3(384), dim3(256), 0, stream>>>(part6, sa, recip);
  final_kernel<<<dim3(1), dim3(256), 0, stream>>>(tl, topv, topi, lse, recip, targets,
                                                  (float*)d_out);
}

// Round 7
// 667.192 us; speedup vs baseline: 1.3934x; 1.3934x over previous
//
#include <hip/hip_runtime.h>
#include <math.h>
#include <type_traits>

#define DIMK 2048
#define NEMB 16384
#define NB 256
#define NR2 1536          // 256*6 neighbor rows
#define NBLK 128          // n-blocks
#define INV_BETA 20.0f
#define NEG_INF (-3.0e38f)

typedef short short8 __attribute__((ext_vector_type(8)));
typedef float f32x4 __attribute__((ext_vector_type(4)));

__device__ __forceinline__ unsigned short f2bf(float f) {
  unsigned u = __float_as_uint(f);
  u += 0x7fffu + ((u >> 16) & 1u);
  return (unsigned short)(u >> 16);
}

__device__ __forceinline__ void ins6(float x, float v[6]) {
  if (x > v[5]) {
    v[5] = x;
#pragma unroll
    for (int j = 5; j > 0; j--) {
      if (v[j] > v[j - 1]) { float tmp = v[j]; v[j] = v[j - 1]; v[j - 1] = tmp; }
    }
  }
}

// top-6 insert with (value desc, index asc) tie-break — matches jax top_k order
__device__ __forceinline__ void ins6i(float x, int xi, float v[6], int vi[6]) {
  if (x > v[5] || (x == v[5] && xi < vi[5])) {
    v[5] = x; vi[5] = xi;
#pragma unroll
    for (int j = 5; j > 0; j--) {
      if (v[j] > v[j - 1] || (v[j] == v[j - 1] && vi[j] < vi[j - 1])) {
        float tv = v[j]; v[j] = v[j - 1]; v[j - 1] = tv;
        int ti = vi[j]; vi[j] = vi[j - 1]; vi[j - 1] = ti;
      }
    }
  }
}

__global__ __launch_bounds__(256) void cvt_kernel(const float* __restrict__ src,
                                                  unsigned short* __restrict__ dst, int n4) {
  int i = blockIdx.x * 256 + threadIdx.x;
  if (i < n4) {
    float4 f = ((const float4*)src)[i];
    ushort4 o;
    o.x = f2bf(f.x); o.y = f2bf(f.y); o.z = f2bf(f.z); o.w = f2bf(f.w);
    ((ushort4*)dst)[i] = o;
  }
}

// Register-prefetch + ds_write double-buffer pipeline (depth 2):
//   half A (k0):   prefetch k0+64 -> stgA | compute buf0 | ds_write stgB(k0+32)->buf1 | barrier
//   half B (k0+32):prefetch k0+96 -> stgB | compute buf1 | ds_write stgA(k0+64)->buf0 | barrier
// Loads are consumed by a ds_write issued ~2 half-iters later -> vmcnt drains on
// data that has had ~400+ cyc to arrive; the barrier's vmcnt(0) is then free.
// This fixes R5 (DMA latency fully exposed at every barrier: 1770 cyc/iter) and
// R6 (2x fetch volume, no sharing, half-step prefetch).
// Subtile = [16 rows x 32 k] bf16 = 1 KB, fragment-contiguous: lane l holds
// (row=l&15, kseg=l>>4) at byte offset l*16 -> conflict-free b128 write & read.
struct EpM0 {                       // logits gemm fused-stats epilogue (~31 KB)
  float ct[32 * 133];
  float p6v[32 * 8 * 6];
  int   p6i[32 * 8 * 6];
  float ms[32 * 8 * 2];
};
struct EpM1 {                       // sims gemm top-6 epilogue (~23.3 KB)
  float ct[32 * 133];
  float p6[32 * 49];
};

// MODE 0: C = X(256xK) * em^T * 20 -> per-(row,128col-block) top6(v,i) + (max,sumexp)
//         tile 64x128, grid (128,4); wr=0, wc=wave (32-col groups)
// MODE 1: C = em[nidx](1536xK) * em^T -> per-(row,128col-block) top-6 partials
//         tile 128x128, grid (128,12); wr=wave>>1, wc=wave&1
template <int MODE>
__global__ __launch_bounds__(256, 3) void gemm_kernel(
    const unsigned short* __restrict__ Abase, const unsigned short* __restrict__ Bbase,
    const int* __restrict__ nidx, float* __restrict__ p1, float* __restrict__ p2,
    float* __restrict__ p3, float* __restrict__ p4) {
  constexpr int MI = 4;
  constexpr int NI = (MODE == 0) ? 2 : 4;
  constexpr int NSUB_A = (MODE == 0) ? 4 : 8;
  constexpr int NSUB = NSUB_A + 8;     // 12 or 16 subtiles per 32-k tile
  constexpr int NA = NSUB / 4;         // per-wave staging loads: 3 or 4

  using Ep = typename std::conditional<MODE == 0, EpM0, EpM1>::type;
  union SMemT {
    unsigned short st[2][NSUB * 512];  // double-buffered staging (24/32 KB)
    Ep ep;
  };
  __shared__ SMemT sm;
  __shared__ int rowIdxSh[128];
  int t = threadIdx.x;
  int lane = t & 63, wave = t >> 6;
  int quad = lane >> 4, l16 = lane & 15;
  int wr = (MODE == 0) ? 0 : (wave >> 1);
  int wc = (MODE == 0) ? wave : (wave & 1);
  int bn = blockIdx.x, bm = blockIdx.y;

  if constexpr (MODE == 1) {
    if (t < 128) rowIdxSh[t] = nidx[bm * 128 + t];
    __syncthreads();
  }

  // per-lane global fragment pointers: subtile s = wave + a*4, lane -> (row=l16, kseg=lane>>4)
  const unsigned short* agp[NA];
  {
    int seg = lane >> 4;
#pragma unroll
    for (int a = 0; a < NA; a++) {
      int s = wave + a * 4;
      const unsigned short* basep;
      size_t goff;
      if (s < NSUB_A) {
        int r = s * 16 + l16;
        int grow = (MODE == 0) ? (bm * 64 + r) : rowIdxSh[r];
        basep = Abase;
        goff = (size_t)grow * DIMK;
      } else {
        int r = (s - NSUB_A) * 16 + l16;
        basep = Bbase;
        goff = (size_t)(bn * 128 + r) * DIMK;
      }
      agp[a] = basep + goff + seg * 8;
    }
  }
  int wroff = lane * 8;  // shorts: lane*16 bytes (write & read offset inside subtile)

  f32x4 acc[MI][NI];
#pragma unroll
  for (int mi = 0; mi < MI; mi++)
#pragma unroll
    for (int ni = 0; ni < NI; ni++) acc[mi][ni] = (f32x4)0.0f;

  short8 stgA[NA], stgB[NA];
#pragma unroll
  for (int a = 0; a < NA; a++) stgA[a] = *(const short8*)(agp[a]);        // k=0
#pragma unroll
  for (int a = 0; a < NA; a++) stgB[a] = *(const short8*)(agp[a] + 32);   // k=32
#pragma unroll
  for (int a = 0; a < NA; a++)
    *(short8*)&sm.st[0][(wave + a * 4) * 512 + wroff] = stgA[a];
  __syncthreads();

#pragma unroll 1
  for (int k0 = 0; k0 < DIMK; k0 += 64) {
    // ---- half A: compute buf0 (k0) ----
    if (k0 + 64 < DIMK) {
#pragma unroll
      for (int a = 0; a < NA; a++) stgA[a] = *(const short8*)(agp[a] + k0 + 64);
    }
    {
      short8 af[MI], bfv[NI];
#pragma unroll
      for (int mi = 0; mi < MI; mi++)
        af[mi] = *(const short8*)&sm.st[0][(wr * MI + mi) * 512 + wroff];
#pragma unroll
      for (int ni = 0; ni < NI; ni++)
        bfv[ni] = *(const short8*)&sm.st[0][(NSUB_A + wc * NI + ni) * 512 + wroff];
#pragma unroll
      for (int mi = 0; mi < MI; mi++)
#pragma unroll
        for (int ni = 0; ni < NI; ni++)
          acc[mi][ni] = __builtin_amdgcn_mfma_f32_16x16x32_bf16(af[mi], bfv[ni], acc[mi][ni], 0, 0, 0);
    }
#pragma unroll
    for (int a = 0; a < NA; a++)
      *(short8*)&sm.st[1][(wave + a * 4) * 512 + wroff] = stgB[a];
    __syncthreads();

    // ---- half B: compute buf1 (k0+32) ----
    if (k0 + 96 < DIMK) {
#pragma unroll
      for (int a = 0; a < NA; a++) stgB[a] = *(const short8*)(agp[a] + k0 + 96);
    }
    {
      short8 af[MI], bfv[NI];
#pragma unroll
      for (int mi = 0; mi < MI; mi++)
        af[mi] = *(const short8*)&sm.st[1][(wr * MI + mi) * 512 + wroff];
#pragma unroll
      for (int ni = 0; ni < NI; ni++)
        bfv[ni] = *(const short8*)&sm.st[1][(NSUB_A + wc * NI + ni) * 512 + wroff];
#pragma unroll
      for (int mi = 0; mi < MI; mi++)
#pragma unroll
        for (int ni = 0; ni < NI; ni++)
          acc[mi][ni] = __builtin_amdgcn_mfma_f32_16x16x32_bf16(af[mi], bfv[ni], acc[mi][ni], 0, 0, 0);
    }
    if (k0 + 64 < DIMK) {
#pragma unroll
      for (int a = 0; a < NA; a++)
        *(short8*)&sm.st[0][(wave + a * 4) * 512 + wroff] = stgA[a];
    }
    __syncthreads();
  }

  if constexpr (MODE == 0) {
    // fused logits stats: per (row, bn) -> top6 (value, global col) + (max, sumexp)
    float* pt6v = p1; float* pt6i_f = p2; float* pmx = p3; float* pse = p4;
    int* pt6i = (int*)pt6i_f;
#pragma unroll
    for (int ph = 0; ph < 2; ph++) {     // 32 rows per phase
#pragma unroll
      for (int mi2 = 0; mi2 < 2; mi2++) {
        int mi = ph * 2 + mi2;
#pragma unroll
        for (int ni = 0; ni < 2; ni++)
#pragma unroll
          for (int rr = 0; rr < 4; rr++)
            sm.ep.ct[(mi2 * 16 + quad * 4 + rr) * 133 + wave * 32 + ni * 16 + l16] =
                acc[mi][ni][rr] * INV_BETA;
      }
      __syncthreads();
      {
        int srow = t & 31, sseg = t >> 5;   // 8 segs x 16 cols
        float vv[16];
        const float* basep = &sm.ep.ct[srow * 133 + sseg * 16];
#pragma unroll
        for (int i = 0; i < 16; i++) vv[i] = basep[i];
        float v[6]; int vi[6];
#pragma unroll
        for (int j = 0; j < 6; j++) { v[j] = NEG_INF; vi[j] = 0x7fffffff; }
        int gcol0 = bn * 128 + sseg * 16;
#pragma unroll
        for (int i = 0; i < 16; i++) ins6i(vv[i], gcol0 + i, v, vi);
        float mloc = v[0];
        float se = 0.f;
#pragma unroll
        for (int i = 0; i < 16; i++) se += expf(vv[i] - mloc);
        int slot = srow * 8 + sseg;
#pragma unroll
        for (int j = 0; j < 6; j++) { sm.ep.p6v[slot * 6 + j] = v[j]; sm.ep.p6i[slot * 6 + j] = vi[j]; }
        sm.ep.ms[slot * 2] = mloc; sm.ep.ms[slot * 2 + 1] = se;
      }
      __syncthreads();
      if (t < 32) {
        float v[6]; int vi[6];
#pragma unroll
        for (int j = 0; j < 6; j++) { v[j] = NEG_INF; vi[j] = 0x7fffffff; }
        float M = NEG_INF, S = 0.f;
#pragma unroll
        for (int s = 0; s < 8; s++) {
          int slot = t * 8 + s;
#pragma unroll
          for (int j = 0; j < 6; j++) ins6i(sm.ep.p6v[slot * 6 + j], sm.ep.p6i[slot * 6 + j], v, vi);
          float mo = sm.ep.ms[slot * 2], so = sm.ep.ms[slot * 2 + 1];
          float Mn = fmaxf(M, mo);
          S = S * expf(M - Mn) + so * expf(mo - Mn);
          M = Mn;
        }
        int rowg = bm * 64 + ph * 32 + t;
        size_t base = ((size_t)rowg * NBLK + bn);
#pragma unroll
        for (int j = 0; j < 6; j++) { pt6v[base * 6 + j] = v[j]; pt6i[base * 6 + j] = vi[j]; }
        pmx[base] = M; pse[base] = S;
      }
      __syncthreads();
    }
  } else {
    float* part6 = p1;
#pragma unroll
    for (int ph = 0; ph < 4; ph++) {       // 32 tile-rows per phase
      int phwr = ph >> 1, phmi0 = (ph & 1) * 2;
      if (wr == phwr) {
#pragma unroll
        for (int mi2 = 0; mi2 < 2; mi2++) {
          int mi = phmi0 + mi2;
#pragma unroll
          for (int ni = 0; ni < 4; ni++)
#pragma unroll
            for (int rr = 0; rr < 4; rr++)
              sm.ep.ct[(mi2 * 16 + quad * 4 + rr) * 133 + wc * 64 + ni * 16 + l16] =
                  acc[mi][ni][rr];
        }
      }
      __syncthreads();
      {
        int srow = t & 31, sseg = t >> 5;   // 8 segs x 16 cols
        float v[6] = {NEG_INF, NEG_INF, NEG_INF, NEG_INF, NEG_INF, NEG_INF};
        const float* basep = &sm.ep.ct[srow * 133 + sseg * 16];
#pragma unroll
        for (int i = 0; i < 16; i++) ins6(basep[i], v);
#pragma unroll
        for (int j = 0; j < 6; j++) sm.ep.p6[srow * 49 + sseg * 6 + j] = v[j];
      }
      __syncthreads();
      if (t < 32) {
        float v[6] = {NEG_INF, NEG_INF, NEG_INF, NEG_INF, NEG_INF, NEG_INF};
        const float* pp = &sm.ep.p6[t * 49];
        for (int i = 0; i < 48; i++) ins6(pp[i], v);
        int rg = bm * 128 + ph * 32 + t;
        float* dst = part6 + ((size_t)rg * NBLK + bn) * 6;
#pragma unroll
        for (int j = 0; j < 6; j++) dst[j] = v[j];
      }
      __syncthreads();
    }
  }
}

// one wave per logit row: merge 128 per-block partials -> global top6 + lse
__global__ __launch_bounds__(256) void mergestats_kernel(
    const float* __restrict__ pt6v, const int* __restrict__ pt6i,
    const float* __restrict__ pmx, const float* __restrict__ pse,
    float* __restrict__ topv, int* __restrict__ topi, float* __restrict__ lse) {
  int gid = blockIdx.x * 256 + threadIdx.x;
  int m = gid >> 6, lane = gid & 63;
  if (m >= NB) return;
  float v[6]; int vi[6];
#pragma unroll
  for (int j = 0; j < 6; j++) { v[j] = NEG_INF; vi[j] = 0x7fffffff; }
  size_t rb = (size_t)m * NBLK;
#pragma unroll
  for (int a = 0; a < 12; a++) {        // 768 entries / 64 lanes
    int e = lane + a * 64;
    ins6i(pt6v[rb * 6 + e], pt6i[rb * 6 + e], v, vi);
  }
  float M = pmx[rb + lane], S = pse[rb + lane];
  {
    float mo = pmx[rb + lane + 64], so = pse[rb + lane + 64];
    float Mn = fmaxf(M, mo);
    S = S * expf(M - Mn) + so * expf(mo - Mn);
    M = Mn;
  }
#pragma unroll
  for (int off = 32; off > 0; off >>= 1) {
    float ov[6]; int oi[6];
#pragma unroll
    for (int j = 0; j < 6; j++) { ov[j] = __shfl_xor(v[j], off, 64); oi[j] = __shfl_xor(vi[j], off, 64); }
#pragma unroll
    for (int j = 0; j < 6; j++) ins6i(ov[j], oi[j], v, vi);
    float oM = __shfl_xor(M, off, 64), oS = __shfl_xor(S, off, 64);
    float Mn = fmaxf(M, oM);
    S = S * expf(M - Mn) + oS * expf(oM - Mn);
    M = Mn;
  }
  if (lane == 0) {
    lse[m] = M + logf(S);
#pragma unroll
    for (int j = 0; j < 6; j++) { topv[m * 6 + j] = v[j]; topi[m * 6 + j] = vi[j]; }
  }
}

// w < NR2: sa[w] = em[topi[w]] . em[anchor];  w in [NR2, NR2+NB): tl[m] = 20 * x[m].em[tgt[m]]
__global__ __launch_bounds__(256) void sa_kernel(const float* __restrict__ em,
                                                 const float* __restrict__ x,
                                                 const int* __restrict__ topi,
                                                 const int* __restrict__ targets,
                                                 float* __restrict__ sa,
                                                 float* __restrict__ tl) {
  int gid = blockIdx.x * 256 + threadIdx.x;
  int w = gid >> 6, lane = gid & 63;
  if (w >= NR2 + NB) return;
  const float* ei; const float* ea;
  if (w < NR2) {
    int m = w / 6;
    ei = em + (size_t)topi[w] * DIMK;
    ea = em + (size_t)topi[m * 6] * DIMK;
  } else {
    int m = w - NR2;
    ei = x + (size_t)m * DIMK;
    ea = em + (size_t)targets[m] * DIMK;
  }
  float s = 0.f;
  for (int d = lane; d < DIMK; d += 64) s += ei[d] * ea[d];
#pragma unroll
  for (int off = 32; off > 0; off >>= 1) s += __shfl_down(s, off, 64);
  if (lane == 0) {
    if (w < NR2) sa[w] = s;
    else tl[w - NR2] = s * INV_BETA;
  }
}

// recip[r] = 1 iff anchor-sim >= 6th-largest of sims row r
// == (count of partial-top6 values strictly greater than sa) < 6
__global__ __launch_bounds__(256) void stage2_kernel(const float* __restrict__ part6,
                                                     const float* __restrict__ sa,
                                                     int* __restrict__ recip) {
  int gid = blockIdx.x * 256 + threadIdx.x;
  int w = gid >> 6, lane = gid & 63;
  if (w >= NR2) return;
  float s = sa[w];
  const float* p = part6 + (size_t)w * (NBLK * 6);
  int cnt = 0;
  for (int i = lane; i < NBLK * 6; i += 64) cnt += (p[i] > s) ? 1 : 0;
#pragma unroll
  for (int off = 32; off > 0; off >>= 1) cnt += __shfl_down(cnt, off, 64);
  if (lane == 0) recip[w] = (cnt < 6) ? 1 : 0;
}

__global__ __launch_bounds__(256) void final_kernel(
    const float* __restrict__ tl_arr, const float* __restrict__ topv,
    const int* __restrict__ topi, const float* __restrict__ lse_arr,
    const int* __restrict__ recip, const int* __restrict__ targets,
    float* __restrict__ out) {
  int m = threadIdx.x;
  float lse = lse_arr[m];
  int tgt = targets[m];
  float tl = tl_arr[m];
  float beta = 0.f, Ps = 0.f, nbp = 0.f;
  bool tin = false;
#pragma unroll
  for (int k = 0; k < 6; k++) {
    int idx = topi[m * 6 + k]; float v = topv[m * 6 + k];
    float p = expf(v - lse);
    if (idx == tgt) { tin = true; beta += (lse - v); Ps += p; }
    else if (recip[m * 6 + k]) { beta += 0.5f * (lse - v); Ps += p; nbp += p; }
  }
  if (!tin) { beta += (lse - tl); Ps += expf(tl - lse); }
  float alpha = 9.2103404f * (1.f - Ps) + 0.6931472f * nbp;
  __shared__ float sA[256], sB2[256];
  sA[m] = alpha; sB2[m] = beta;
  __syncthreads();
  for (int s = 128; s > 0; s >>= 1) {
    if (m < s) { sA[m] += sA[m + s]; sB2[m] += sB2[m + s]; }
    __syncthreads();
  }
  if (m == 0) { out[0] = 0.05f * sA[0] / 256.f; out[1] = sB2[0] / 256.f; }
}

extern "C" void kernel_launch(void* const* d_in, const int* in_sizes, int n_in,
                              void* d_out, int out_size, void* d_ws, size_t ws_size,
                              hipStream_t stream) {
  const float* x = (const float*)d_in[0];
  const float* em = (const float*)d_in[1];
  const int* targets = (const int*)d_in[2];
  char* ws = (char*)d_ws;
  unsigned short* em_bf = (unsigned short*)ws;                 // 67108864 B
  unsigned short* x_bf  = (unsigned short*)(ws + 67108864);    // 1048576 B
  float* pt6v   = (float*)(ws + 68157440);                     // 786432 B
  float* pt6i_f = (float*)(ws + 68943872);                     // 786432 B
  float* pmx    = (float*)(ws + 69730304);                     // 131072 B
  float* pse    = (float*)(ws + 69861376);                     // 131072 B
  float* part6  = (float*)(ws + 69992448);                     // 4718592 B
  float* topv   = (float*)(ws + 74711040);                     // 6144 B
  int*   topi   = (int*)  (ws + 74717184);                     // 6144 B
  float* lse    = (float*)(ws + 74723328);                     // 1024 B
  float* sa     = (float*)(ws + 74724352);                     // 6144 B
  int*   recip  = (int*)  (ws + 74730496);                     // 6144 B
  float* tl     = (float*)(ws + 74736640);                     // 1024 B

  cvt_kernel<<<dim3(32768), dim3(256), 0, stream>>>(em, em_bf, NEMB * DIMK / 4);
  cvt_kernel<<<dim3(512), dim3(256), 0, stream>>>(x, x_bf, NB * DIMK / 4);
  gemm_kernel<0><<<dim3(128, 4), dim3(256), 0, stream>>>(x_bf, em_bf, (const int*)nullptr,
                                                         pt6v, pt6i_f, pmx, pse);
  mergestats_kernel<<<dim3(64), dim3(256), 0, stream>>>(pt6v, (const int*)pt6i_f, pmx, pse,
                                                        topv, topi, lse);
  sa_kernel<<<dim3(448), dim3(256), 0, stream>>>(em, x, topi, targets, sa, tl);
  gemm_kernel<1><<<dim3(128, 12), dim3(256), 0, stream>>>(em_bf, em_bf, topi,
                                                          part6, (float*)nullptr,
                                                          (float*)nullptr, (float*)nullptr);
  stage2_kernel<<<dim3(384), dim3(256), 0, stream>>>(part6, sa, recip);
  final_kernel<<<dim3(1), dim3(256), 0, stream>>>(tl, topv, topi, lse, recip, targets,
                                                  (float*)d_out);
}